// Round 1
// baseline (200.370 us; speedup 1.0000x reference)
//
#include <hip/hip_runtime.h>

// ---- problem constants (from reference) ----
#define BB   8
#define HL   128
#define WL   128
#define HH   1024
#define WH   1024
#define CH   3
#define AH   120
#define AW   120
#define NSP  (AH * AW)      // 14400 sample-space size
#define NP   10             // N_PATCHES
#define PH   100
#define PW   100
#define RFD  8              // receptive field

// ---- output layout (concatenated flat, reference return order) ----
// patches (8,10,100,100,3) | sampled_attention (8,10) | offsets (8,10,2) | samples (8,10,2)
#define OUT_SAMP (BB * NP * PH * PW * CH)     // 2400000
#define OUT_OFF  (OUT_SAMP + BB * NP)         // 2400080
#define OUT_SMP  (OUT_OFF + BB * NP * 2)      // 2400240

// ============================================================
// Kernel 1: per-batch Gumbel top-k (without replacement) + scalar outputs
// One block per batch. Keys staged in LDS; 10 rounds of block argmax
// (tie-break: lower index first, matching jax.lax.top_k).
// ============================================================
__global__ __launch_bounds__(256) void topk_kernel(
    const float* __restrict__ att,
    const float* __restrict__ unoise,
    float* __restrict__ out,
    int* __restrict__ corners /* BB*NP*2 in d_ws */) {

    __shared__ float s_key[NSP];     // 57.6 KB
    __shared__ float s_rv[256];
    __shared__ int   s_ri[256];

    const int b = blockIdx.x;
    const int t = threadIdx.x;
    const float* a = att + (size_t)b * NSP;
    const float* u = unoise + (size_t)b * NSP;

    // key = log(max(att,1e-20)) + gumbel(u),  gumbel = -log(-log(clip(u)))
    for (int i = t; i < NSP; i += 256) {
        float uv = fminf(fmaxf(u[i], 1e-6f), 1.0f - 1e-6f);
        float g  = -logf(-logf(uv));
        s_key[i] = logf(fmaxf(a[i], 1e-20f)) + g;
    }
    __syncthreads();

    for (int k = 0; k < NP; ++k) {
        // local argmax over strided range (prefer lower index on tie)
        float bv = -INFINITY;
        int   bi = 0x7fffffff;
        for (int i = t; i < NSP; i += 256) {
            float v = s_key[i];
            if (v > bv || (v == bv && i < bi)) { bv = v; bi = i; }
        }
        s_rv[t] = bv; s_ri[t] = bi;
        __syncthreads();
        // block tree reduce with same tie-break
        for (int s = 128; s > 0; s >>= 1) {
            if (t < s) {
                float v2 = s_rv[t + s]; int i2 = s_ri[t + s];
                if (v2 > s_rv[t] || (v2 == s_rv[t] && i2 < s_ri[t])) {
                    s_rv[t] = v2; s_ri[t] = i2;
                }
            }
            __syncthreads();
        }
        if (t == 0) {
            const int best = s_ri[0];
            const int sy = best / AW;
            const int sx = best % AW;
            // prev_patch/space = [120/120,120/120] = 1 ; scales = [8,8]
            // offsets = (s + RF/2) * 8  — exact small integers in fp32
            const float oy = (float)(sy + RFD / 2) * 8.0f;
            const float ox = (float)(sx + RFD / 2) * 8.0f;
            const int o = b * NP + k;
            out[OUT_SAMP + o]          = a[best];     // sampled_attention (exact copy)
            out[OUT_OFF + o * 2 + 0]   = oy;
            out[OUT_OFF + o * 2 + 1]   = ox;
            out[OUT_SMP + o * 2 + 0]   = (float)sy;   // samples (int written as float)
            out[OUT_SMP + o * 2 + 1]   = (float)sx;
            // dynamic_slice clamp: [0, HH-PH] = [0, 924]
            int cy = (int)oy; int cx = (int)ox;
            cy = min(max(cy, 0), HH - PH);
            cx = min(max(cx, 0), WH - PW);
            corners[o * 2 + 0] = cy;
            corners[o * 2 + 1] = cx;
            s_key[best] = -INFINITY;                  // remove for next round
        }
        __syncthreads();
    }
}

// ============================================================
// Kernel 2: patch gather-copy. One float4 (4 floats) per thread.
// Row segment = 100 px * 3 ch = 300 floats = 75 float4, contiguous in
// both src (NHWC x_high) and dst. corner*3 is always a multiple of 4
// floats ((s+4)*8*3 or 924*3) -> 16B-aligned float4 loads/stores.
// ============================================================
#define NQUAD  (PW * CH / 4)               // 75
#define TOTALQ (BB * NP * PH * NQUAD)      // 600000

__global__ __launch_bounds__(256) void patch_kernel(
    const float* __restrict__ xh,
    const int* __restrict__ corners,
    float* __restrict__ out) {

    const int q = blockIdx.x * 256 + threadIdx.x;
    if (q >= TOTALQ) return;
    const int quad = q % NQUAD;
    const int tmp  = q / NQUAD;
    const int row  = tmp % PH;
    const int p    = tmp / PH;          // b*NP + n
    const int b    = p / NP;
    const int cy   = corners[p * 2 + 0];
    const int cx   = corners[p * 2 + 1];

    const float4* src = (const float4*)(xh + (((size_t)b * HH + cy + row) * WH + cx) * CH) + quad;
    float4*       dst = (float4*)(out + ((size_t)p * PH + row) * (size_t)(PW * CH)) + quad;
    *dst = *src;
}

extern "C" void kernel_launch(void* const* d_in, const int* in_sizes, int n_in,
                              void* d_out, int out_size, void* d_ws, size_t ws_size,
                              hipStream_t stream) {
    // inputs: 0=x_low (unused, shape baked into constants), 1=x_high,
    //         2=attention, 3=uniform_noise — all float32
    const float* xh  = (const float*)d_in[1];
    const float* att = (const float*)d_in[2];
    const float* un  = (const float*)d_in[3];
    float* out = (float*)d_out;
    int* corners = (int*)d_ws;   // BB*NP*2 ints of scratch

    topk_kernel<<<BB, 256, 0, stream>>>(att, un, out, corners);
    patch_kernel<<<(TOTALQ + 255) / 256, 256, 0, stream>>>(xh, corners, out);
}

// Round 2
// 153.468 us; speedup vs baseline: 1.3056x; 1.3056x over previous
//
#include <hip/hip_runtime.h>

// ---- problem constants (from reference) ----
#define BB   8
#define HH   1024
#define WH   1024
#define CH   3
#define AH   120
#define AW   120
#define NSP  (AH * AW)      // 14400 sample-space size
#define NP   10             // N_PATCHES
#define PH   100
#define PW   100
#define RFD  8              // receptive field

// ---- output layout (concatenated flat, reference return order) ----
// patches (8,10,100,100,3) | sampled_attention (8,10) | offsets (8,10,2) | samples (8,10,2)
#define OUT_SAMP (BB * NP * PH * PW * CH)     // 2400000
#define OUT_OFF  (OUT_SAMP + BB * NP)         // 2400080
#define OUT_SMP  (OUT_OFF + BB * NP * 2)      // 2400240

// ---- stage-1 decomposition ----
#define WPB   15            // waves per batch
#define CHUNK 960           // keys per wave = 15 * 64
#define EPL   15            // elements per lane
#define NC    (WPB * NP)    // 150 candidates per batch

// ============================================================
// Stage 1: per-wave top-10 over a 960-key chunk, all in registers.
// grid = (WPB, BB), block = 64 (one wave). No LDS, no barriers.
// Key math is bit-identical to the verified round-1 kernel.
// ============================================================
__global__ __launch_bounds__(64) void topk_stage1(
    const float* __restrict__ att,
    const float* __restrict__ unoise,
    float* __restrict__ cand_v,
    int* __restrict__ cand_i) {

    const int wave = blockIdx.x;         // 0..14
    const int b    = blockIdx.y;         // 0..7
    const int lane = threadIdx.x;        // 0..63
    const int base = wave * CHUNK;       // chunk offset within batch
    const float* a = att    + (size_t)b * NSP;
    const float* u = unoise + (size_t)b * NSP;

    // compute keys: coalesced loads, 15 independent chains -> latency hidden
    float key[EPL];
    #pragma unroll
    for (int j = 0; j < EPL; ++j) {
        const int i = base + j * 64 + lane;          // always < 14400
        float uv = fminf(fmaxf(u[i], 1e-6f), 1.0f - 1e-6f);
        float g  = -logf(-logf(uv));
        key[j] = logf(fmaxf(a[i], 1e-20f)) + g;
    }

    float rv[NP]; int ri[NP];
    #pragma unroll
    for (int k = 0; k < NP; ++k) {
        // lane-local argmax (strict > keeps lowest j == lowest global index)
        float bv = key[0]; int bj = 0;
        #pragma unroll
        for (int j = 1; j < EPL; ++j)
            if (key[j] > bv) { bv = key[j]; bj = j; }
        int li = base + bj * 64 + lane;              // global sample index

        // wave butterfly argmax, tie-break lower index
        #pragma unroll
        for (int off = 32; off > 0; off >>= 1) {
            float ov = __shfl_xor(bv, off);
            int   oi = __shfl_xor(li, off);
            if (ov > bv || (ov == bv && oi < li)) { bv = ov; li = oi; }
        }

        // invalidate winner (unrolled to avoid dynamic register indexing)
        const int ll = li - base;                    // 0..959
        const int jw = ll >> 6;
        const int lw = ll & 63;
        if (lane == lw) {
            #pragma unroll
            for (int j = 0; j < EPL; ++j)
                if (j == jw) key[j] = -INFINITY;
        }
        rv[k] = bv; ri[k] = li;
    }

    // lane k (k<10) writes candidate k — static-index select
    float wv = 0.f; int wi = 0;
    #pragma unroll
    for (int k = 0; k < NP; ++k)
        if (lane == k) { wv = rv[k]; wi = ri[k]; }
    if (lane < NP) {
        const int o = (b * WPB + wave) * NP + lane;
        cand_v[o] = wv;
        cand_i[o] = wi;
    }
}

// ============================================================
// Stage 2: one wave per batch merges 150 candidates -> final top-10,
// writes sampled_attention / offsets / samples / corners.
// ============================================================
__global__ __launch_bounds__(64) void topk_stage2(
    const float* __restrict__ att,
    const float* __restrict__ cand_v,
    const int* __restrict__ cand_i,
    float* __restrict__ out,
    int* __restrict__ corners) {

    const int b    = blockIdx.x;
    const int lane = threadIdx.x;

    float v[3]; int ix[3];
    #pragma unroll
    for (int c = 0; c < 3; ++c) {
        const int p = c * 64 + lane;
        const bool ok = p < NC;
        v[c]  = ok ? cand_v[b * NC + p] : -INFINITY;
        ix[c] = ok ? cand_i[b * NC + p] : 0x7fffffff;
    }

    int ri[NP];
    #pragma unroll
    for (int k = 0; k < NP; ++k) {
        float bv = v[0]; int bi = ix[0];
        #pragma unroll
        for (int c = 1; c < 3; ++c)
            if (v[c] > bv || (v[c] == bv && ix[c] < bi)) { bv = v[c]; bi = ix[c]; }
        #pragma unroll
        for (int off = 32; off > 0; off >>= 1) {
            float ov = __shfl_xor(bv, off);
            int   oi = __shfl_xor(bi, off);
            if (ov > bv || (ov == bv && oi < bi)) { bv = ov; bi = oi; }
        }
        // invalidate winner (sample indices are unique across chunks)
        #pragma unroll
        for (int c = 0; c < 3; ++c)
            if (ix[c] == bi) { v[c] = -INFINITY; ix[c] = 0x7fffffff; }
        ri[k] = bi;
    }

    // lane k (k<10) handles output k
    int best = 0;
    #pragma unroll
    for (int k = 0; k < NP; ++k)
        if (lane == k) best = ri[k];

    if (lane < NP) {
        const int sy = best / AW;
        const int sx = best % AW;
        // prev_patch/space = 1, scales = 8 -> offsets = (s + RF/2) * 8, exact fp32
        const float oy = (float)(sy + RFD / 2) * 8.0f;
        const float ox = (float)(sx + RFD / 2) * 8.0f;
        const int o = b * NP + lane;
        out[OUT_SAMP + o]        = att[(size_t)b * NSP + best];
        out[OUT_OFF + o * 2 + 0] = oy;
        out[OUT_OFF + o * 2 + 1] = ox;
        out[OUT_SMP + o * 2 + 0] = (float)sy;
        out[OUT_SMP + o * 2 + 1] = (float)sx;
        int cy = (int)oy, cx = (int)ox;
        cy = min(max(cy, 0), HH - PH);               // dynamic_slice clamp
        cx = min(max(cx, 0), WH - PW);
        corners[o * 2 + 0] = cy;
        corners[o * 2 + 1] = cx;
    }
}

// ============================================================
// Patch gather-copy: one float4 per thread. Row segment = 300 floats
// = 75 float4, contiguous in src (NHWC) and dst; corner*3 floats is
// always 16B-aligned ((s+4)*8*3 or 924*3).
// ============================================================
#define NQUAD  (PW * CH / 4)               // 75
#define TOTALQ (BB * NP * PH * NQUAD)      // 600000

__global__ __launch_bounds__(256) void patch_kernel(
    const float* __restrict__ xh,
    const int* __restrict__ corners,
    float* __restrict__ out) {

    const int q = blockIdx.x * 256 + threadIdx.x;
    if (q >= TOTALQ) return;
    const int quad = q % NQUAD;
    const int tmp  = q / NQUAD;
    const int row  = tmp % PH;
    const int p    = tmp / PH;          // b*NP + n
    const int b    = p / NP;
    const int cy   = corners[p * 2 + 0];
    const int cx   = corners[p * 2 + 1];

    const float4* src = (const float4*)(xh + (((size_t)b * HH + cy + row) * WH + cx) * CH) + quad;
    float4*       dst = (float4*)(out + ((size_t)p * PH + row) * (size_t)(PW * CH)) + quad;
    *dst = *src;
}

extern "C" void kernel_launch(void* const* d_in, const int* in_sizes, int n_in,
                              void* d_out, int out_size, void* d_ws, size_t ws_size,
                              hipStream_t stream) {
    // inputs: 0=x_low (unused), 1=x_high, 2=attention, 3=uniform_noise — all f32
    const float* xh  = (const float*)d_in[1];
    const float* att = (const float*)d_in[2];
    const float* un  = (const float*)d_in[3];
    float* out = (float*)d_out;

    // workspace layout: cand_v (8*150 f32) | cand_i (8*150 i32) | corners (160 i32)
    float* cand_v  = (float*)d_ws;
    int*   cand_i  = (int*)(cand_v + BB * NC);
    int*   corners = (int*)(cand_i + BB * NC);

    topk_stage1<<<dim3(WPB, BB), 64, 0, stream>>>(att, un, cand_v, cand_i);
    topk_stage2<<<BB, 64, 0, stream>>>(att, cand_v, cand_i, out, corners);
    patch_kernel<<<(TOTALQ + 255) / 256, 256, 0, stream>>>(xh, corners, out);
}